// Round 1
// baseline (592.131 us; speedup 1.0000x reference)
//
#include <hip/hip_runtime.h>
#include <stdint.h>

// Problem constants (B,N,H,W) = (4,256,256,256)
#define BATCH 4
#define NCH   256
#define HH    256
#define WW    256
#define HWSZ  (HH * WW)          // 65536
#define NPIX  (BATCH * HWSZ)     // 262144 output-mean denominator

// ---------------------------------------------------------------------------
// Kernel 1: one block per (b,n) channel. Scan the 64K-int channel of
// target_centers (exactly one element == 1) and write its flat index (over
// H*W) into centers[bn]. int4 loads -> 1 KiB per wave-instruction, fully
// coalesced; the compare is almost always false so the body is execz-skipped.
// ---------------------------------------------------------------------------
__global__ __launch_bounds__(256) void find_centers(
    const int* __restrict__ tc, int* __restrict__ centers)
{
    const int bn  = blockIdx.x;             // 0..1023
    const int tid = threadIdx.x;            // 0..255
    const int4* p = (const int4*)(tc + (size_t)bn * HWSZ);

    int found = -1;
    #pragma unroll 4
    for (int i = 0; i < HWSZ / 4 / 256; ++i) {   // 64 iters
        const int idx = i * 256 + tid;
        const int4 v = p[idx];
        if (v.x | v.y | v.z | v.w) {
            int off = v.x ? 0 : (v.y ? 1 : (v.z ? 2 : 3));
            found = idx * 4 + off;
        }
    }
    if (found >= 0) centers[bn] = found;    // exactly one writer per bn
}

// ---------------------------------------------------------------------------
// Kernel 2: 512 blocks; block covers 2 rows (b fixed). Thread tid handles an
// int2 pair of pixels: row = h0 + (tid>>7), w = (tid&127)*2. Loops n=0..255
// with coalesced int2 loads of targets; centers+pad cached in LDS.
// ---------------------------------------------------------------------------
__global__ __launch_bounds__(256) void loss_kernel(
    const float* __restrict__ pred,
    const int*   __restrict__ targets,
    const unsigned char* __restrict__ padraw,   // layout auto-detected
    const int*   __restrict__ centers,
    float*       __restrict__ out)
{
    __shared__ int   cpack[NCH];
    __shared__ int   modeflag;     // 1 => pad_mask stored as uint8, 0 => int32
    __shared__ float wsum[4];

    const int tid = threadIdx.x;
    if (tid == 0) modeflag = 0;
    __syncthreads();

    // --- detect pad_mask ABI layout from the first 1024 bytes (safe under
    // both interpretations). uint8 layout: random 0/1 bytes at all offsets ->
    // some word has nonzero upper 3 bytes. int32 layout: words are 0/1 only.
    {
        const unsigned int wv = ((const unsigned int*)padraw)[tid];
        if (wv & 0xFFFFFF00u) modeflag = 1;     // benign same-value race
    }
    __syncthreads();

    const int b  = blockIdx.x >> 7;            // 128 blocks per batch
    const int h0 = (blockIdx.x & 127) << 1;

    // --- load this batch's centers + pad flags into LDS (n == tid)
    {
        const int n = tid;
        const int cidx = centers[b * NCH + n];          // cr*256 + cc
        int pad;
        if (modeflag) pad = (padraw[b * NCH + n] != 0);
        else          pad = (((const int*)padraw)[b * NCH + n] != 0);
        cpack[n] = (cidx & 0xFFFF) | (pad << 30);
    }
    __syncthreads();

    const int hrow = h0 + (tid >> 7);
    const int wcol = (tid & 127) << 1;

    const int* base = targets + (size_t)b * NCH * HWSZ + hrow * WW + wcol;

    int   tsum0 = 0, tsum1 = 0;
    float imp0 = 0.f, imp1 = 0.f;

    #pragma unroll 8
    for (int n = 0; n < NCH; ++n) {
        const int2 v = *(const int2*)(base + (size_t)n * HWSZ);
        const int c  = cpack[n];
        const int cr = (c >> 8) & 255;
        const int cc = c & 255;
        const int dh  = hrow - cr;
        const int dw0 = wcol - cc;
        const int dw1 = dw0 + 1;
        const int dh2 = dh * dh;
        const float f0 = (float)(dh2 + dw0 * dw0) + 1e-6f;
        const float f1 = (float)(dh2 + dw1 * dw1) + 1e-6f;
        tsum0 += v.x;
        tsum1 += v.y;
        const int valid = ((c & (1 << 30)) == 0);
        if (v.x & valid) imp0 += __builtin_amdgcn_rcpf(f0);
        if (v.y & valid) imp1 += __builtin_amdgcn_rcpf(f1);
    }

    // --- epilogue: importance coeff (+ bitwise-NOT semantics) and stable BCE
    const float it0 = imp0 + (float)(~tsum0) * 0.5f;
    const float it1 = imp1 + (float)(~tsum1) * 0.5f;

    const int pix = b * HWSZ + hrow * WW + wcol;
    const float x0 = pred[pix];
    const float x1 = pred[pix + 1];
    const float bce0 = fmaxf(x0, 0.f) - x0 * (float)tsum0 + log1pf(expf(-fabsf(x0)));
    const float bce1 = fmaxf(x1, 0.f) - x1 * (float)tsum1 + log1pf(expf(-fabsf(x1)));

    float contrib = bce0 * it0 + bce1 * it1;

    // --- block reduction: wave64 shuffle, then 4-wave LDS combine
    #pragma unroll
    for (int o = 32; o > 0; o >>= 1) contrib += __shfl_down(contrib, o, 64);
    const int wave = tid >> 6;
    if ((tid & 63) == 0) wsum[wave] = contrib;
    __syncthreads();
    if (tid == 0) {
        const float s = wsum[0] + wsum[1] + wsum[2] + wsum[3];
        atomicAdd(out, s * (1.0f / (float)NPIX));
    }
}

extern "C" void kernel_launch(void* const* d_in, const int* in_sizes, int n_in,
                              void* d_out, int out_size, void* d_ws, size_t ws_size,
                              hipStream_t stream)
{
    const float* pred = (const float*)d_in[0];               // [B,H,W] f32
    const int*   tc   = (const int*)d_in[1];                 // [B,N,H,W] i32
    const int*   tg   = (const int*)d_in[2];                 // [B,N,H,W] i32
    const unsigned char* pm = (const unsigned char*)d_in[3]; // [B,N] bool
    float* out   = (float*)d_out;
    int* centers = (int*)d_ws;                               // 1024 ints

    hipMemsetAsync(d_out, 0, sizeof(float), stream);
    find_centers<<<BATCH * NCH, 256, 0, stream>>>(tc, centers);
    loss_kernel<<<BATCH * HH / 2, 256, 0, stream>>>(pred, tg, pm, centers, out);
}

// Round 2
// 508.531 us; speedup vs baseline: 1.1644x; 1.1644x over previous
//
#include <hip/hip_runtime.h>
#include <stdint.h>

// Problem constants (B,N,H,W) = (4,256,256,256)
#define BATCH 4
#define NCH   256
#define HH    256
#define WW    256
#define HWSZ  (HH * WW)          // 65536
#define NPIX  (BATCH * HWSZ)     // 262144 output-mean denominator

// ---------------------------------------------------------------------------
// Kernel 1: one block per (b,n) channel. Scan the 64K-int channel of
// target_centers (exactly one element == 1) and write its flat index into
// centers[bn]. int4 loads, branch body almost always execz-skipped.
// ---------------------------------------------------------------------------
__global__ __launch_bounds__(256) void find_centers(
    const int* __restrict__ tc, int* __restrict__ centers)
{
    const int bn  = blockIdx.x;             // 0..1023
    const int tid = threadIdx.x;            // 0..255
    const int4* p = (const int4*)(tc + (size_t)bn * HWSZ);

    int found = -1;
    #pragma unroll 8
    for (int i = 0; i < HWSZ / 4 / 256; ++i) {   // 64 iters
        const int idx = i * 256 + tid;
        const int4 v = p[idx];
        if (v.x | v.y | v.z | v.w) {
            int off = v.x ? 0 : (v.y ? 1 : (v.z ? 2 : 3));
            found = idx * 4 + off;
        }
    }
    if (found >= 0) centers[bn] = found;    // exactly one writer per bn
}

// ---------------------------------------------------------------------------
// Kernel 2: 1024 blocks = one per (b, row). 16 waves/CU for HBM latency
// hiding. Thread tid owns pixel (hrow, tid). Per-n data precomputed in LDS:
//   cinfo[n] = { (hrow-cr)^2 + 1e-6  (or +inf if padded -> rcp()=0),
//                (float)cc }
// Inner loop is branchless, no integer multiplies, unroll 16 keeps 16 dword
// loads in flight per wave.
// ---------------------------------------------------------------------------
__global__ __launch_bounds__(256) void loss_kernel(
    const float* __restrict__ pred,
    const int*   __restrict__ targets,
    const unsigned char* __restrict__ padraw,   // layout auto-detected
    const int*   __restrict__ centers,
    float*       __restrict__ out)
{
    __shared__ float2 cinfo[NCH];
    __shared__ int    modeflag;   // 1 => pad_mask stored as uint8, 0 => int32
    __shared__ float  wsum[4];

    const int tid = threadIdx.x;
    if (tid == 0) modeflag = 0;
    __syncthreads();

    // --- detect pad_mask ABI layout (identical to the verified R1 logic).
    // uint8 layout: 256 words of 4 random 0/1 bytes -> some word has nonzero
    // upper 3 bytes (P[miss] ~ 8^-256). int32 layout: words are 0/1 only.
    {
        const unsigned int wv = ((const unsigned int*)padraw)[tid];
        if (wv & 0xFFFFFF00u) modeflag = 1;     // benign same-value race
    }
    __syncthreads();

    const int b    = blockIdx.x >> 8;           // 256 blocks per batch
    const int hrow = blockIdx.x & 255;

    // --- per-n precompute into LDS (n == tid); hrow is block-uniform
    {
        const int n    = tid;
        const int cidx = centers[b * NCH + n];  // cr*256 + cc, < 65536
        const int cr   = cidx >> 8;
        const int cc   = cidx & 255;
        int pad;
        if (modeflag) pad = (padraw[b * NCH + n] != 0);
        else          pad = (((const int*)padraw)[b * NCH + n] != 0);
        const int dh = hrow - cr;
        float fdh2e = (float)(dh * dh) + 1e-6f;
        if (pad) fdh2e = __builtin_inff();      // rcp(inf + dw^2) == 0
        cinfo[n] = make_float2(fdh2e, (float)cc);
    }
    __syncthreads();

    const float wcolf = (float)tid;
    const int* base = targets + (size_t)b * NCH * HWSZ + hrow * WW + tid;

    int   tsum = 0;
    float imp  = 0.f;

    #pragma unroll 16
    for (int n = 0; n < NCH; ++n) {
        const int    v = base[(size_t)n * HWSZ];    // coalesced 256 B/wave
        const float2 c = cinfo[n];                  // LDS broadcast
        const float fdw = wcolf - c.y;
        const float f   = __builtin_fmaf(fdw, fdw, c.x);
        imp = __builtin_fmaf((float)v, __builtin_amdgcn_rcpf(f), imp);
        tsum += v;
    }

    // --- epilogue: importance coeff (~tsum bitwise-NOT semantics) + BCE
    const float it = __builtin_fmaf((float)(~tsum), 0.5f, imp);

    const float x   = pred[b * HWSZ + hrow * WW + tid];
    const float bce = fmaxf(x, 0.f) - x * (float)tsum + log1pf(expf(-fabsf(x)));

    float contrib = bce * it;

    // --- block reduction: wave64 shuffle, then 4-wave LDS combine
    #pragma unroll
    for (int o = 32; o > 0; o >>= 1) contrib += __shfl_down(contrib, o, 64);
    const int wave = tid >> 6;
    if ((tid & 63) == 0) wsum[wave] = contrib;
    __syncthreads();
    if (tid == 0) {
        const float s = wsum[0] + wsum[1] + wsum[2] + wsum[3];
        atomicAdd(out, s * (1.0f / (float)NPIX));
    }
}

extern "C" void kernel_launch(void* const* d_in, const int* in_sizes, int n_in,
                              void* d_out, int out_size, void* d_ws, size_t ws_size,
                              hipStream_t stream)
{
    const float* pred = (const float*)d_in[0];               // [B,H,W] f32
    const int*   tc   = (const int*)d_in[1];                 // [B,N,H,W] i32
    const int*   tg   = (const int*)d_in[2];                 // [B,N,H,W] i32
    const unsigned char* pm = (const unsigned char*)d_in[3]; // [B,N] bool
    float* out   = (float*)d_out;
    int* centers = (int*)d_ws;                               // 1024 ints

    hipMemsetAsync(d_out, 0, sizeof(float), stream);
    find_centers<<<BATCH * NCH, 256, 0, stream>>>(tc, centers);
    loss_kernel<<<BATCH * HH, 256, 0, stream>>>(pred, tg, pm, centers, out);
}

// Round 3
// 507.366 us; speedup vs baseline: 1.1671x; 1.0023x over previous
//
#include <hip/hip_runtime.h>
#include <stdint.h>

// Problem constants (B,N,H,W) = (4,256,256,256)
#define BATCH 4
#define NCH   256
#define HH    256
#define WW    256
#define HWSZ  (HH * WW)          // 65536
#define NPIX  (BATCH * HWSZ)     // 262144 output-mean denominator

// ---------------------------------------------------------------------------
// Kernel 1: one block per (b,n) channel. The channel holds exactly one 1
// among 0s, so flat_index = sum(value * index) over the channel — computed
// BRANCHLESSLY (v_mad chain). The R2 version's per-iteration `if` on the
// loaded value forced a vmcnt drain + s_cbranch_execz every iteration,
// capping memory-level parallelism at ~1 load/wave (~2.5x off HBM roofline).
// Branchless form lets the compiler keep all 8 unrolled int4 loads in
// flight (8 KiB/wave x 16 waves/CU = 128 KiB in flight).
// ---------------------------------------------------------------------------
__global__ __launch_bounds__(256) void find_centers(
    const int* __restrict__ tc, int* __restrict__ centers)
{
    __shared__ int wsum[4];
    const int bn  = blockIdx.x;             // 0..1023
    const int tid = threadIdx.x;            // 0..255
    const int4* p = (const int4*)(tc + (size_t)bn * HWSZ);

    int acc = 0;
    #pragma unroll 8
    for (int i = 0; i < HWSZ / 4 / 256; ++i) {   // 64 iters
        const int idx = i * 256 + tid;
        const int4 v = p[idx];
        const int b4 = idx * 4;                  // <= 65532 < 2^24
        acc += v.x * b4 + v.y * (b4 + 1) + v.z * (b4 + 2) + v.w * (b4 + 3);
    }

    // wave64 shuffle reduce, then 4-wave LDS combine
    #pragma unroll
    for (int o = 32; o > 0; o >>= 1) acc += __shfl_down(acc, o, 64);
    if ((tid & 63) == 0) wsum[tid >> 6] = acc;
    __syncthreads();
    if (tid == 0) centers[bn] = wsum[0] + wsum[1] + wsum[2] + wsum[3];
}

// ---------------------------------------------------------------------------
// Kernel 2 (UNCHANGED from R2 — kept identical to isolate the find_centers
// delta): 1024 blocks = one per (b, row). Branchless inner loop; per-n
// {(h-cr)^2+eps (or +inf if padded), (float)cc} precomputed in LDS.
// ---------------------------------------------------------------------------
__global__ __launch_bounds__(256) void loss_kernel(
    const float* __restrict__ pred,
    const int*   __restrict__ targets,
    const unsigned char* __restrict__ padraw,   // layout auto-detected
    const int*   __restrict__ centers,
    float*       __restrict__ out)
{
    __shared__ float2 cinfo[NCH];
    __shared__ int    modeflag;   // 1 => pad_mask stored as uint8, 0 => int32
    __shared__ float  wsum[4];

    const int tid = threadIdx.x;
    if (tid == 0) modeflag = 0;
    __syncthreads();

    // --- detect pad_mask ABI layout. uint8 layout: 256 words of 4 random
    // 0/1 bytes -> some word has nonzero upper 3 bytes. int32: words 0/1.
    {
        const unsigned int wv = ((const unsigned int*)padraw)[tid];
        if (wv & 0xFFFFFF00u) modeflag = 1;     // benign same-value race
    }
    __syncthreads();

    const int b    = blockIdx.x >> 8;           // 256 blocks per batch
    const int hrow = blockIdx.x & 255;

    // --- per-n precompute into LDS (n == tid); hrow is block-uniform
    {
        const int n    = tid;
        const int cidx = centers[b * NCH + n];  // cr*256 + cc, < 65536
        const int cr   = cidx >> 8;
        const int cc   = cidx & 255;
        int pad;
        if (modeflag) pad = (padraw[b * NCH + n] != 0);
        else          pad = (((const int*)padraw)[b * NCH + n] != 0);
        const int dh = hrow - cr;
        float fdh2e = (float)(dh * dh) + 1e-6f;
        if (pad) fdh2e = __builtin_inff();      // rcp(inf + dw^2) == 0
        cinfo[n] = make_float2(fdh2e, (float)cc);
    }
    __syncthreads();

    const float wcolf = (float)tid;
    const int* base = targets + (size_t)b * NCH * HWSZ + hrow * WW + tid;

    int   tsum = 0;
    float imp  = 0.f;

    #pragma unroll 16
    for (int n = 0; n < NCH; ++n) {
        const int    v = base[(size_t)n * HWSZ];    // coalesced 256 B/wave
        const float2 c = cinfo[n];                  // LDS broadcast
        const float fdw = wcolf - c.y;
        const float f   = __builtin_fmaf(fdw, fdw, c.x);
        imp = __builtin_fmaf((float)v, __builtin_amdgcn_rcpf(f), imp);
        tsum += v;
    }

    // --- epilogue: importance coeff (~tsum bitwise-NOT semantics) + BCE
    const float it = __builtin_fmaf((float)(~tsum), 0.5f, imp);

    const float x   = pred[b * HWSZ + hrow * WW + tid];
    const float bce = fmaxf(x, 0.f) - x * (float)tsum + log1pf(expf(-fabsf(x)));

    float contrib = bce * it;

    // --- block reduction: wave64 shuffle, then 4-wave LDS combine
    #pragma unroll
    for (int o = 32; o > 0; o >>= 1) contrib += __shfl_down(contrib, o, 64);
    const int wave = tid >> 6;
    if ((tid & 63) == 0) wsum[wave] = contrib;
    __syncthreads();
    if (tid == 0) {
        const float s = wsum[0] + wsum[1] + wsum[2] + wsum[3];
        atomicAdd(out, s * (1.0f / (float)NPIX));
    }
}

extern "C" void kernel_launch(void* const* d_in, const int* in_sizes, int n_in,
                              void* d_out, int out_size, void* d_ws, size_t ws_size,
                              hipStream_t stream)
{
    const float* pred = (const float*)d_in[0];               // [B,H,W] f32
    const int*   tc   = (const int*)d_in[1];                 // [B,N,H,W] i32
    const int*   tg   = (const int*)d_in[2];                 // [B,N,H,W] i32
    const unsigned char* pm = (const unsigned char*)d_in[3]; // [B,N] bool
    float* out   = (float*)d_out;
    int* centers = (int*)d_ws;                               // 1024 ints

    hipMemsetAsync(d_out, 0, sizeof(float), stream);
    find_centers<<<BATCH * NCH, 256, 0, stream>>>(tc, centers);
    loss_kernel<<<BATCH * HH, 256, 0, stream>>>(pred, tg, pm, centers, out);
}